// Round 3
// baseline (426.346 us; speedup 1.0000x reference)
//
#include <hip/hip_runtime.h>
#include <hip/hip_bf16.h>

typedef __bf16 bf16;
typedef __attribute__((ext_vector_type(8))) __bf16 bf16x8;
typedef __attribute__((ext_vector_type(4))) __bf16 bf16x4;
typedef __attribute__((ext_vector_type(4))) float f32x4;

#define M_TOK 32768   // B*S = 8*4096
#define D_    512
#define N_QKV 1536
#define CHUNK 8192    // token chunk: keeps workspace ~44 MB
#define SCALE_ 0.125f

// ---------------- fp32 -> bf16 convert (vectorized) ----------------
__global__ __launch_bounds__(256) void cvt_bf16(const float* __restrict__ in,
                                                bf16* __restrict__ out, int n4) {
  int i = blockIdx.x * 256 + threadIdx.x;
  if (i >= n4) return;
  f32x4 v = ((const f32x4*)in)[i];
  bf16x4 o;
  o[0] = (bf16)v[0]; o[1] = (bf16)v[1]; o[2] = (bf16)v[2]; o[3] = (bf16)v[3];
  ((bf16x4*)out)[i] = o;
}

// ---------------- transpose+convert: fp32 in [K][N] -> bf16 out [N][K] ----------------
__global__ __launch_bounds__(256) void transpose_cvt(const float* __restrict__ in,
                                                     bf16* __restrict__ out,
                                                     int K, int N) {
  __shared__ float tile[32][33];
  int n0 = blockIdx.x * 32, k0 = blockIdx.y * 32;
  int tx = threadIdx.x, ty = threadIdx.y;
  for (int i = 0; i < 32; i += 8)
    tile[ty + i][tx] = in[(size_t)(k0 + ty + i) * N + n0 + tx];
  __syncthreads();
  for (int i = 0; i < 32; i += 8)
    out[(size_t)(n0 + ty + i) * K + k0 + tx] = (bf16)tile[tx][ty + i];
}

// ---------------- GEMM: C = A[M,K](bf16) * Bt[N,K](bf16)^T + bias(f32) (+resid f32) ----
// 128x128 tile, 4 waves, each wave 64x64 (4x4 of 16x16x32 bf16 MFMA).
// CT = output element type (bf16 for Y, float for final out).
template <typename CT>
__global__ __launch_bounds__(256) void gemm_bt(const bf16* __restrict__ A,
                                               const bf16* __restrict__ Bt,
                                               const float* __restrict__ bias,
                                               const float* __restrict__ resid,
                                               CT* __restrict__ C,
                                               int M, int N, int K) {
  __shared__ __align__(16) bf16 sA[128 * 32];
  __shared__ __align__(16) bf16 sB[128 * 32];

  const int tid = threadIdx.x;
  const int w = tid >> 6;        // wave 0..3
  const int l = tid & 63;        // lane
  const int m0 = blockIdx.y * 128;
  const int n0 = blockIdx.x * 128;
  const int wrow = w >> 1, wcol = w & 1;

  f32x4 acc[4][4];
#pragma unroll
  for (int i = 0; i < 4; ++i)
#pragma unroll
    for (int j = 0; j < 4; ++j) {
      f32x4 z = {0.f, 0.f, 0.f, 0.f};
      acc[i][j] = z;
    }

  // staging: per wave-round 1024B = 16 rows of 64B; lane l -> row l/4, chunk (l&3)*8 elems
  const int srow = l >> 2;
  const int schunk = (l & 3) * 8;

  for (int kt = 0; kt < K; kt += 32) {
#pragma unroll
    for (int r = 0; r < 2; ++r) {
      int row = r * 64 + w * 16;
      const bf16* gp = A + (size_t)(m0 + row + srow) * K + kt + schunk;
      bf16* lp = &sA[row * 32];
      __builtin_amdgcn_global_load_lds(
          (__attribute__((address_space(1))) void*)(gp),
          (__attribute__((address_space(3))) void*)(lp), 16, 0, 0);
    }
#pragma unroll
    for (int r = 0; r < 2; ++r) {
      int row = r * 64 + w * 16;
      const bf16* gp = Bt + (size_t)(n0 + row + srow) * K + kt + schunk;
      bf16* lp = &sB[row * 32];
      __builtin_amdgcn_global_load_lds(
          (__attribute__((address_space(1))) void*)(gp),
          (__attribute__((address_space(3))) void*)(lp), 16, 0, 0);
    }
    __syncthreads();

    bf16x8 af[4], bfr[4];
    const int fr = l & 15;
    const int fk = (l >> 4) * 8;
#pragma unroll
    for (int i = 0; i < 4; ++i)
      af[i] = *(const bf16x8*)&sA[(wrow * 64 + i * 16 + fr) * 32 + fk];
#pragma unroll
    for (int j = 0; j < 4; ++j)
      bfr[j] = *(const bf16x8*)&sB[(wcol * 64 + j * 16 + fr) * 32 + fk];
#pragma unroll
    for (int i = 0; i < 4; ++i)
#pragma unroll
      for (int j = 0; j < 4; ++j)
        acc[i][j] = __builtin_amdgcn_mfma_f32_16x16x32_bf16(af[i], bfr[j], acc[i][j], 0, 0, 0);
    __syncthreads();
  }

  // epilogue: D[row=(l>>4)*4+r][col=l&15]
  const int col = l & 15;
  const int rbase = (l >> 4) * 4;
#pragma unroll
  for (int j = 0; j < 4; ++j) {
    int n = n0 + wcol * 64 + j * 16 + col;
    float bv = bias[n];
#pragma unroll
    for (int i = 0; i < 4; ++i) {
#pragma unroll
      for (int r = 0; r < 4; ++r) {
        int m = m0 + wrow * 64 + i * 16 + rbase + r;
        float v = acc[i][j][r] + bv;
        if (resid) v += resid[(size_t)m * N + n];
        C[(size_t)m * N + n] = (CT)v;
      }
    }
  }
}

// ---------------- per-token/head: O = softmax((q-k)*s, over d) * v ----------------
// one wave per (token, head); lane = dim j in [0,64)
__global__ __launch_bounds__(256) void softmax_mul(const bf16* __restrict__ Y,
                                                   bf16* __restrict__ O,
                                                   int TOK) {
  int gw = blockIdx.x * 4 + (threadIdx.x >> 6);
  int l = threadIdx.x & 63;
  int t = gw >> 3;
  int h = gw & 7;
  if (t >= TOK) return;
  const bf16* row = Y + (size_t)t * N_QKV + h * 64 + l;
  float q = (float)row[0];
  float k = (float)row[512];
  float v = (float)row[1024];
  float s = (q - k) * SCALE_;
  float m = s;
#pragma unroll
  for (int off = 32; off > 0; off >>= 1) m = fmaxf(m, __shfl_xor(m, off));
  float e = __expf(s - m);
  float sum = e;
#pragma unroll
  for (int off = 32; off > 0; off >>= 1) sum += __shfl_xor(sum, off);
  O[(size_t)t * D_ + h * 64 + l] = (bf16)(e / sum * v);
}

extern "C" void kernel_launch(void* const* d_in, const int* in_sizes, int n_in,
                              void* d_out, int out_size, void* d_ws, size_t ws_size,
                              hipStream_t stream) {
  const float* x     = (const float*)d_in[0];   // [32768, 512] fp32
  const float* Wqkv  = (const float*)d_in[1];   // [512, 1536] fp32
  const float* bqkv  = (const float*)d_in[2];   // [1536] fp32
  const float* Wproj = (const float*)d_in[3];   // [512, 512] fp32
  const float* bproj = (const float*)d_in[4];   // [512] fp32
  float* out = (float*)d_out;                   // [32768, 512] fp32

  // workspace layout (~44.3 MB):
  char* ws = (char*)d_ws;
  bf16* Wq_t = (bf16*)ws;                                   // [1536,512] bf16  1.57 MB
  bf16* Wp_t = (bf16*)(ws + (size_t)N_QKV * D_ * 2);        // [512,512]  bf16  0.52 MB
  char* p = ws + (size_t)N_QKV * D_ * 2 + (size_t)D_ * D_ * 2;
  bf16* Xc = (bf16*)p;                                      // [CHUNK,512] bf16 8.4 MB
  bf16* Yc = (bf16*)(p + (size_t)CHUNK * D_ * 2);           // [CHUNK,1536] bf16 25.2 MB
  bf16* Oc = (bf16*)(p + (size_t)CHUNK * D_ * 2 + (size_t)CHUNK * N_QKV * 2); // 8.4 MB

  transpose_cvt<<<dim3(N_QKV / 32, D_ / 32), dim3(32, 8), 0, stream>>>(Wqkv, Wq_t, D_, N_QKV);
  transpose_cvt<<<dim3(D_ / 32, D_ / 32), dim3(32, 8), 0, stream>>>(Wproj, Wp_t, D_, D_);

  for (int c0 = 0; c0 < M_TOK; c0 += CHUNK) {
    const float* xc = x + (size_t)c0 * D_;

    cvt_bf16<<<(CHUNK * D_ / 4 + 255) / 256, 256, 0, stream>>>(xc, Xc, CHUNK * D_ / 4);

    gemm_bt<bf16><<<dim3(N_QKV / 128, CHUNK / 128), 256, 0, stream>>>(
        Xc, Wq_t, bqkv, nullptr, Yc, CHUNK, N_QKV, D_);

    softmax_mul<<<(CHUNK * 8) / 4, 256, 0, stream>>>(Yc, Oc, CHUNK);

    gemm_bt<float><<<dim3(D_ / 128, CHUNK / 128), 256, 0, stream>>>(
        Oc, Wp_t, bproj, xc, out + (size_t)c0 * D_, CHUNK, D_, D_);
  }
}

// Round 4
// 318.311 us; speedup vs baseline: 1.3394x; 1.3394x over previous
//
#include <hip/hip_runtime.h>
#include <hip/hip_bf16.h>

typedef __bf16 bf16;
typedef __attribute__((ext_vector_type(8))) __bf16 bf16x8;
typedef __attribute__((ext_vector_type(4))) __bf16 bf16x4;
typedef __attribute__((ext_vector_type(4))) float f32x4;

#define M_TOK 32768   // B*S = 8*4096
#define D_    512
#define N_QKV 1536
#define SCALE_ 0.125f

// ---------------- fp32 -> bf16 convert (vectorized) ----------------
__global__ __launch_bounds__(256) void cvt_bf16(const float* __restrict__ in,
                                                bf16* __restrict__ out, int n4) {
  int i = blockIdx.x * 256 + threadIdx.x;
  if (i >= n4) return;
  f32x4 v = ((const f32x4*)in)[i];
  bf16x4 o;
  o[0] = (bf16)v[0]; o[1] = (bf16)v[1]; o[2] = (bf16)v[2]; o[3] = (bf16)v[3];
  ((bf16x4*)out)[i] = o;
}

// ---------------- transpose+convert: fp32 in [K][N] -> bf16 out [N][K] ----------------
// PERM=1: head-major column permutation for W_qkv:
//   orig col n (=qkv*512 + h*64 + c) -> out row h*192 + qkv*64 + c
template <int PERM>
__global__ __launch_bounds__(256) void transpose_cvt(const float* __restrict__ in,
                                                     bf16* __restrict__ out,
                                                     int K, int N) {
  __shared__ float tile[32][33];
  int n0 = blockIdx.x * 32, k0 = blockIdx.y * 32;
  int tx = threadIdx.x, ty = threadIdx.y;
  for (int i = 0; i < 32; i += 8)
    tile[ty + i][tx] = in[(size_t)(k0 + ty + i) * N + n0 + tx];
  __syncthreads();
  for (int i = 0; i < 32; i += 8) {
    int n = n0 + ty + i;
    int np = n;
    if (PERM) {
      int h = (n & 511) >> 6, qkv = n >> 9;
      np = h * 192 + qkv * 64 + (n & 63);
    }
    out[(size_t)np * K + k0 + tx] = (bf16)tile[tx][ty + i];
  }
}

// ---------------- fused GEMM1 + per-head softmax ----------------
// A [M,512] bf16, Bt [1536(perm),512] bf16. Block = 128 rows x 192 cols (one head).
// 4 waves; wave w owns rows w*32..w*32+31, all 192 cols (q=tiles 0-3, k=4-7, v=8-11).
// Epilogue: O[m, h*64+c] = softmax_c((q-k)*scale) * v, written bf16.
__global__ __launch_bounds__(256) void gemm_qkv_softmax(const bf16* __restrict__ A,
                                                        const bf16* __restrict__ Bt,
                                                        const float* __restrict__ bqkv,
                                                        bf16* __restrict__ O) {
  __shared__ __align__(16) bf16 sA[128 * 32];
  __shared__ __align__(16) bf16 sB[192 * 32];

  const int tid = threadIdx.x;
  const int w = tid >> 6;
  const int l = tid & 63;
  const int m0 = blockIdx.y * 128;
  const int h  = blockIdx.x;           // head 0..7
  const int n0 = h * 192;

  f32x4 acc[2][12];
#pragma unroll
  for (int i = 0; i < 2; ++i)
#pragma unroll
    for (int j = 0; j < 12; ++j) {
      f32x4 z = {0.f, 0.f, 0.f, 0.f};
      acc[i][j] = z;
    }

  const int srow = l >> 2;             // 16 rows per wave-issue
  const int schunk = (l & 3) * 8;
  const int fr = l & 15;
  const int fk = (l >> 4) * 8;

  for (int kt = 0; kt < D_; kt += 32) {
#pragma unroll
    for (int r = 0; r < 2; ++r) {
      int row = r * 64 + w * 16;
      const bf16* gp = A + (size_t)(m0 + row + srow) * D_ + kt + schunk;
      __builtin_amdgcn_global_load_lds(
          (__attribute__((address_space(1))) void*)(gp),
          (__attribute__((address_space(3))) void*)(&sA[row * 32]), 16, 0, 0);
    }
#pragma unroll
    for (int r = 0; r < 3; ++r) {
      int row = r * 64 + w * 16;
      const bf16* gp = Bt + (size_t)(n0 + row + srow) * D_ + kt + schunk;
      __builtin_amdgcn_global_load_lds(
          (__attribute__((address_space(1))) void*)(gp),
          (__attribute__((address_space(3))) void*)(&sB[row * 32]), 16, 0, 0);
    }
    __syncthreads();

    bf16x8 af0 = *(const bf16x8*)&sA[(w * 32 + 0  + fr) * 32 + fk];
    bf16x8 af1 = *(const bf16x8*)&sA[(w * 32 + 16 + fr) * 32 + fk];
#pragma unroll
    for (int j = 0; j < 12; ++j) {
      bf16x8 bfj = *(const bf16x8*)&sB[(j * 16 + fr) * 32 + fk];
      acc[0][j] = __builtin_amdgcn_mfma_f32_16x16x32_bf16(af0, bfj, acc[0][j], 0, 0, 0);
      acc[1][j] = __builtin_amdgcn_mfma_f32_16x16x32_bf16(af1, bfj, acc[1][j], 0, 0, 0);
    }
    __syncthreads();
  }

  // biases for this lane's 4 q/k/v columns (col within head = jq*16 + (l&15))
  float bq[4], bk[4], bv[4];
#pragma unroll
  for (int jq = 0; jq < 4; ++jq) {
    int c = h * 64 + jq * 16 + fr;
    bq[jq] = bqkv[c];
    bk[jq] = bqkv[512 + c];
    bv[jq] = bqkv[1024 + c];
  }

  const int rbase = (l >> 4) * 4;
#pragma unroll
  for (int i = 0; i < 2; ++i) {
#pragma unroll
    for (int r = 0; r < 4; ++r) {
      float sc[4];
#pragma unroll
      for (int jq = 0; jq < 4; ++jq)
        sc[jq] = (acc[i][jq][r] + bq[jq] - acc[i][jq + 4][r] - bk[jq]) * SCALE_;
      float mx = fmaxf(fmaxf(sc[0], sc[1]), fmaxf(sc[2], sc[3]));
#pragma unroll
      for (int off = 1; off < 16; off <<= 1) mx = fmaxf(mx, __shfl_xor(mx, off));
      float e[4];
      float sum = 0.f;
#pragma unroll
      for (int jq = 0; jq < 4; ++jq) { e[jq] = __expf(sc[jq] - mx); sum += e[jq]; }
#pragma unroll
      for (int off = 1; off < 16; off <<= 1) sum += __shfl_xor(sum, off);
      float inv = 1.0f / sum;
      int m = m0 + w * 32 + i * 16 + rbase + r;
#pragma unroll
      for (int jq = 0; jq < 4; ++jq) {
        float o = e[jq] * inv * (acc[i][jq + 8][r] + bv[jq]);
        O[(size_t)m * D_ + h * 64 + jq * 16 + fr] = (bf16)o;
      }
    }
  }
}

// ---------------- GEMM2: out = resid + O * Wp^T + bias (fp32 out) ----------------
__global__ __launch_bounds__(256) void gemm_bt_f32(const bf16* __restrict__ A,
                                                   const bf16* __restrict__ Bt,
                                                   const float* __restrict__ bias,
                                                   const float* __restrict__ resid,
                                                   float* __restrict__ C,
                                                   int M, int N, int K) {
  __shared__ __align__(16) bf16 sA[128 * 32];
  __shared__ __align__(16) bf16 sB[128 * 32];

  const int tid = threadIdx.x;
  const int w = tid >> 6;
  const int l = tid & 63;
  const int m0 = blockIdx.y * 128;
  const int n0 = blockIdx.x * 128;
  const int wrow = w >> 1, wcol = w & 1;

  f32x4 acc[4][4];
#pragma unroll
  for (int i = 0; i < 4; ++i)
#pragma unroll
    for (int j = 0; j < 4; ++j) {
      f32x4 z = {0.f, 0.f, 0.f, 0.f};
      acc[i][j] = z;
    }

  const int srow = l >> 2;
  const int schunk = (l & 3) * 8;

  for (int kt = 0; kt < K; kt += 32) {
#pragma unroll
    for (int r = 0; r < 2; ++r) {
      int row = r * 64 + w * 16;
      const bf16* gp = A + (size_t)(m0 + row + srow) * K + kt + schunk;
      __builtin_amdgcn_global_load_lds(
          (__attribute__((address_space(1))) void*)(gp),
          (__attribute__((address_space(3))) void*)(&sA[row * 32]), 16, 0, 0);
    }
#pragma unroll
    for (int r = 0; r < 2; ++r) {
      int row = r * 64 + w * 16;
      const bf16* gp = Bt + (size_t)(n0 + row + srow) * K + kt + schunk;
      __builtin_amdgcn_global_load_lds(
          (__attribute__((address_space(1))) void*)(gp),
          (__attribute__((address_space(3))) void*)(&sB[row * 32]), 16, 0, 0);
    }
    __syncthreads();

    bf16x8 af[4], bfr[4];
    const int fr = l & 15;
    const int fk = (l >> 4) * 8;
#pragma unroll
    for (int i = 0; i < 4; ++i)
      af[i] = *(const bf16x8*)&sA[(wrow * 64 + i * 16 + fr) * 32 + fk];
#pragma unroll
    for (int j = 0; j < 4; ++j)
      bfr[j] = *(const bf16x8*)&sB[(wcol * 64 + j * 16 + fr) * 32 + fk];
#pragma unroll
    for (int i = 0; i < 4; ++i)
#pragma unroll
      for (int j = 0; j < 4; ++j)
        acc[i][j] = __builtin_amdgcn_mfma_f32_16x16x32_bf16(af[i], bfr[j], acc[i][j], 0, 0, 0);
    __syncthreads();
  }

  const int col = l & 15;
  const int rbase = (l >> 4) * 4;
#pragma unroll
  for (int j = 0; j < 4; ++j) {
    int n = n0 + wcol * 64 + j * 16 + col;
    float bv = bias[n];
#pragma unroll
    for (int i = 0; i < 4; ++i) {
#pragma unroll
      for (int r = 0; r < 4; ++r) {
        int m = m0 + wrow * 64 + i * 16 + rbase + r;
        C[(size_t)m * N + n] = acc[i][j][r] + bv + resid[(size_t)m * N + n];
      }
    }
  }
}

extern "C" void kernel_launch(void* const* d_in, const int* in_sizes, int n_in,
                              void* d_out, int out_size, void* d_ws, size_t ws_size,
                              hipStream_t stream) {
  const float* x     = (const float*)d_in[0];   // [32768, 512]
  const float* Wqkv  = (const float*)d_in[1];   // [512, 1536]
  const float* bqkv  = (const float*)d_in[2];   // [1536]
  const float* Wproj = (const float*)d_in[3];   // [512, 512]
  const float* bproj = (const float*)d_in[4];   // [512]
  float* out = (float*)d_out;

  // workspace (~69.2 MB; ws is ~256 MB per harness poison size)
  char* ws = (char*)d_ws;
  bf16* Wq_t = (bf16*)ws;                               // [1536,512] perm  1.57 MB
  bf16* Wp_t = (bf16*)(ws + (size_t)N_QKV * D_ * 2);    // [512,512]        0.52 MB
  char* p = ws + (size_t)N_QKV * D_ * 2 + (size_t)D_ * D_ * 2;
  bf16* Xb = (bf16*)p;                                  // [32768,512] bf16 33.6 MB
  bf16* O  = (bf16*)(p + (size_t)M_TOK * D_ * 2);       // [32768,512] bf16 33.6 MB

  transpose_cvt<1><<<dim3(N_QKV / 32, D_ / 32), dim3(32, 8), 0, stream>>>(Wqkv, Wq_t, D_, N_QKV);
  transpose_cvt<0><<<dim3(D_ / 32, D_ / 32), dim3(32, 8), 0, stream>>>(Wproj, Wp_t, D_, D_);

  cvt_bf16<<<(M_TOK * D_ / 4 + 255) / 256, 256, 0, stream>>>(x, Xb, M_TOK * D_ / 4);

  gemm_qkv_softmax<<<dim3(8, M_TOK / 128), 256, 0, stream>>>(Xb, Wq_t, bqkv, O);

  gemm_bt_f32<<<dim3(D_ / 128, M_TOK / 128), 256, 0, stream>>>(
      O, Wp_t, bproj, x, out, M_TOK, D_, D_);
}

// Round 5
// 236.984 us; speedup vs baseline: 1.7990x; 1.3432x over previous
//
#include <hip/hip_runtime.h>
#include <hip/hip_bf16.h>

typedef __bf16 bf16;
typedef __attribute__((ext_vector_type(8))) __bf16 bf16x8;
typedef __attribute__((ext_vector_type(4))) __bf16 bf16x4;
typedef __attribute__((ext_vector_type(4))) float f32x4;

#define M_TOK 32768   // B*S = 8*4096
#define D_    512
#define N_QKV 1536
#define BK    64
#define SCALE_ 0.125f

#define AS1 __attribute__((address_space(1)))
#define AS3 __attribute__((address_space(3)))

// ---------------- fp32 -> bf16 convert (vectorized) ----------------
__global__ __launch_bounds__(256) void cvt_bf16(const float* __restrict__ in,
                                                bf16* __restrict__ out, int n4) {
  int i = blockIdx.x * 256 + threadIdx.x;
  if (i >= n4) return;
  f32x4 v = ((const f32x4*)in)[i];
  bf16x4 o;
  o[0] = (bf16)v[0]; o[1] = (bf16)v[1]; o[2] = (bf16)v[2]; o[3] = (bf16)v[3];
  ((bf16x4*)out)[i] = o;
}

// ---------------- transpose+convert: fp32 in [K][N] -> bf16 out [N][K] ----------------
// PERM=1: head-major column permutation for W_qkv:
//   orig col n (=qkv*512 + h*64 + c) -> out row h*192 + qkv*64 + c
template <int PERM>
__global__ __launch_bounds__(256) void transpose_cvt(const float* __restrict__ in,
                                                     bf16* __restrict__ out,
                                                     int K, int N) {
  __shared__ float tile[32][33];
  int n0 = blockIdx.x * 32, k0 = blockIdx.y * 32;
  int tx = threadIdx.x, ty = threadIdx.y;
  for (int i = 0; i < 32; i += 8)
    tile[ty + i][tx] = in[(size_t)(k0 + ty + i) * N + n0 + tx];
  __syncthreads();
  for (int i = 0; i < 32; i += 8) {
    int n = n0 + ty + i;
    int np = n;
    if (PERM) {
      int h = (n & 511) >> 6, qkv = n >> 9;
      np = h * 192 + qkv * 64 + (n & 63);
    }
    out[(size_t)np * K + k0 + tx] = (bf16)tile[tx][ty + i];
  }
}

// ---------------- fused GEMM1 + per-head softmax ----------------
// A [M,512] bf16, Bt [1536(perm),512] bf16. Block = 128 rows x 192 cols (one head).
// BK=64, XOR-swizzled LDS (chunk slot = chunk ^ (row&7)) -> conflict-free ds_read_b128.
// grid: x = row-block (fast, 256 == 0 mod 8 -> same row-tile lands on same XCD
// across heads => A L2 reuse), y = head.
__global__ __launch_bounds__(256) void gemm_qkv_softmax(const bf16* __restrict__ A,
                                                        const bf16* __restrict__ Bt,
                                                        const float* __restrict__ bqkv,
                                                        bf16* __restrict__ O) {
  __shared__ __align__(16) bf16 sA[128 * BK];   // 16 KB
  __shared__ __align__(16) bf16 sB[192 * BK];   // 24 KB

  const int tid = threadIdx.x;
  const int w = tid >> 6;
  const int l = tid & 63;
  const int m0 = blockIdx.x * 128;
  const int h  = blockIdx.y;           // head 0..7
  const int n0 = h * 192;

  f32x4 acc[2][12];
#pragma unroll
  for (int i = 0; i < 2; ++i)
#pragma unroll
    for (int j = 0; j < 12; ++j) {
      f32x4 z = {0.f, 0.f, 0.f, 0.f};
      acc[i][j] = z;
    }

  // staging lane map: issue covers 8 rows x 128B; lane l -> row l>>3,
  // LDS slot l&7 which must hold global chunk (l&7)^(l>>3)
  const int srow = l >> 3;
  const int schunk = ((l & 7) ^ (l >> 3)) * 8;   // elem offset of staged chunk

  const int fr = l & 15;
  const int fkc = l >> 4;              // 16B-chunk within a 64B K-half: 0..3
  const int frs = fr & 7;              // row&7 for all fragment rows (bases are %8==0)

  for (int kt = 0; kt < D_; kt += BK) {
#pragma unroll
    for (int q = 0; q < 4; ++q) {      // A rows w*32 .. +32
      int rowb = w * 32 + q * 8;
      const bf16* gp = A + (size_t)(m0 + rowb + srow) * D_ + kt + schunk;
      __builtin_amdgcn_global_load_lds((AS1 void*)gp, (AS3 void*)&sA[rowb * BK], 16, 0, 0);
    }
#pragma unroll
    for (int q = 0; q < 6; ++q) {      // B rows w*48 .. +48
      int rowb = w * 48 + q * 8;
      const bf16* gp = Bt + (size_t)(n0 + rowb + srow) * D_ + kt + schunk;
      __builtin_amdgcn_global_load_lds((AS1 void*)gp, (AS3 void*)&sB[rowb * BK], 16, 0, 0);
    }
    __syncthreads();

#pragma unroll
    for (int kk = 0; kk < 2; ++kk) {
      const int sw = (((kk << 2) | fkc) ^ frs) * 8;  // swizzled elem offset in row
      bf16x8 af0 = *(const bf16x8*)&sA[(w * 32 + 0  + fr) * BK + sw];
      bf16x8 af1 = *(const bf16x8*)&sA[(w * 32 + 16 + fr) * BK + sw];
#pragma unroll
      for (int j = 0; j < 12; ++j) {
        bf16x8 bfj = *(const bf16x8*)&sB[(j * 16 + fr) * BK + sw];
        acc[0][j] = __builtin_amdgcn_mfma_f32_16x16x32_bf16(af0, bfj, acc[0][j], 0, 0, 0);
        acc[1][j] = __builtin_amdgcn_mfma_f32_16x16x32_bf16(af1, bfj, acc[1][j], 0, 0, 0);
      }
    }
    __syncthreads();
  }

  // biases for this lane's 4 q/k/v columns (col within head = jq*16 + fr)
  float bq[4], bk[4], bv[4];
#pragma unroll
  for (int jq = 0; jq < 4; ++jq) {
    int c = h * 64 + jq * 16 + fr;
    bq[jq] = bqkv[c];
    bk[jq] = bqkv[512 + c];
    bv[jq] = bqkv[1024 + c];
  }

  const int rbase = (l >> 4) * 4;
#pragma unroll
  for (int i = 0; i < 2; ++i) {
#pragma unroll
    for (int r = 0; r < 4; ++r) {
      float sc[4];
#pragma unroll
      for (int jq = 0; jq < 4; ++jq)
        sc[jq] = (acc[i][jq][r] + bq[jq] - acc[i][jq + 4][r] - bk[jq]) * SCALE_;
      float mx = fmaxf(fmaxf(sc[0], sc[1]), fmaxf(sc[2], sc[3]));
#pragma unroll
      for (int off = 1; off < 16; off <<= 1) mx = fmaxf(mx, __shfl_xor(mx, off));
      float e[4];
      float sum = 0.f;
#pragma unroll
      for (int jq = 0; jq < 4; ++jq) { e[jq] = __expf(sc[jq] - mx); sum += e[jq]; }
#pragma unroll
      for (int off = 1; off < 16; off <<= 1) sum += __shfl_xor(sum, off);
      float inv = 1.0f / sum;
      int m = m0 + w * 32 + i * 16 + rbase + r;
#pragma unroll
      for (int jq = 0; jq < 4; ++jq) {
        float o = e[jq] * inv * (acc[i][jq + 8][r] + bv[jq]);
        O[(size_t)m * D_ + h * 64 + jq * 16 + fr] = (bf16)o;
      }
    }
  }
}

// ---------------- GEMM2: out = resid + O * Wp^T + bias (fp32 out) ----------------
// BK=64 + XOR swizzle; grid x = row-block (fast) for same-XCD A reuse across col-blocks.
__global__ __launch_bounds__(256) void gemm_bt_f32(const bf16* __restrict__ A,
                                                   const bf16* __restrict__ Bt,
                                                   const float* __restrict__ bias,
                                                   const float* __restrict__ resid,
                                                   float* __restrict__ C,
                                                   int M, int N, int K) {
  __shared__ __align__(16) bf16 sA[128 * BK];
  __shared__ __align__(16) bf16 sB[128 * BK];

  const int tid = threadIdx.x;
  const int w = tid >> 6;
  const int l = tid & 63;
  const int m0 = blockIdx.x * 128;
  const int n0 = blockIdx.y * 128;
  const int wrow = w >> 1, wcol = w & 1;

  f32x4 acc[4][4];
#pragma unroll
  for (int i = 0; i < 4; ++i)
#pragma unroll
    for (int j = 0; j < 4; ++j) {
      f32x4 z = {0.f, 0.f, 0.f, 0.f};
      acc[i][j] = z;
    }

  const int srow = l >> 3;
  const int schunk = ((l & 7) ^ (l >> 3)) * 8;
  const int fr = l & 15;
  const int fkc = l >> 4;
  const int frs = fr & 7;

  for (int kt = 0; kt < K; kt += BK) {
#pragma unroll
    for (int q = 0; q < 4; ++q) {
      int rowb = w * 32 + q * 8;
      const bf16* gp = A + (size_t)(m0 + rowb + srow) * K + kt + schunk;
      __builtin_amdgcn_global_load_lds((AS1 void*)gp, (AS3 void*)&sA[rowb * BK], 16, 0, 0);
    }
#pragma unroll
    for (int q = 0; q < 4; ++q) {
      int rowb = w * 32 + q * 8;
      const bf16* gp = Bt + (size_t)(n0 + rowb + srow) * K + kt + schunk;
      __builtin_amdgcn_global_load_lds((AS1 void*)gp, (AS3 void*)&sB[rowb * BK], 16, 0, 0);
    }
    __syncthreads();

#pragma unroll
    for (int kk = 0; kk < 2; ++kk) {
      const int sw = (((kk << 2) | fkc) ^ frs) * 8;
      bf16x8 af[4], bfr[4];
#pragma unroll
      for (int i = 0; i < 4; ++i)
        af[i] = *(const bf16x8*)&sA[(wrow * 64 + i * 16 + fr) * BK + sw];
#pragma unroll
      for (int j = 0; j < 4; ++j)
        bfr[j] = *(const bf16x8*)&sB[(wcol * 64 + j * 16 + fr) * BK + sw];
#pragma unroll
      for (int i = 0; i < 4; ++i)
#pragma unroll
        for (int j = 0; j < 4; ++j)
          acc[i][j] = __builtin_amdgcn_mfma_f32_16x16x32_bf16(af[i], bfr[j], acc[i][j], 0, 0, 0);
    }
    __syncthreads();
  }

  const int col = l & 15;
  const int rbase = (l >> 4) * 4;
#pragma unroll
  for (int j = 0; j < 4; ++j) {
    int n = n0 + wcol * 64 + j * 16 + col;
    float bv = bias[n];
#pragma unroll
    for (int i = 0; i < 4; ++i) {
#pragma unroll
      for (int r = 0; r < 4; ++r) {
        int m = m0 + wrow * 64 + i * 16 + rbase + r;
        C[(size_t)m * N + n] = acc[i][j][r] + bv + resid[(size_t)m * N + n];
      }
    }
  }
}

extern "C" void kernel_launch(void* const* d_in, const int* in_sizes, int n_in,
                              void* d_out, int out_size, void* d_ws, size_t ws_size,
                              hipStream_t stream) {
  const float* x     = (const float*)d_in[0];   // [32768, 512]
  const float* Wqkv  = (const float*)d_in[1];   // [512, 1536]
  const float* bqkv  = (const float*)d_in[2];   // [1536]
  const float* Wproj = (const float*)d_in[3];   // [512, 512]
  const float* bproj = (const float*)d_in[4];   // [512]
  float* out = (float*)d_out;

  // workspace (~69.2 MB)
  char* ws = (char*)d_ws;
  bf16* Wq_t = (bf16*)ws;                               // [1536,512] perm  1.57 MB
  bf16* Wp_t = (bf16*)(ws + (size_t)N_QKV * D_ * 2);    // [512,512]        0.52 MB
  char* p = ws + (size_t)N_QKV * D_ * 2 + (size_t)D_ * D_ * 2;
  bf16* Xb = (bf16*)p;                                  // [32768,512] bf16 33.6 MB
  bf16* O  = (bf16*)(p + (size_t)M_TOK * D_ * 2);       // [32768,512] bf16 33.6 MB

  transpose_cvt<1><<<dim3(N_QKV / 32, D_ / 32), dim3(32, 8), 0, stream>>>(Wqkv, Wq_t, D_, N_QKV);
  transpose_cvt<0><<<dim3(D_ / 32, D_ / 32), dim3(32, 8), 0, stream>>>(Wproj, Wp_t, D_, D_);

  cvt_bf16<<<(M_TOK * D_ / 4 + 255) / 256, 256, 0, stream>>>(x, Xb, M_TOK * D_ / 4);

  gemm_qkv_softmax<<<dim3(M_TOK / 128, 8), 256, 0, stream>>>(Xb, Wq_t, bqkv, O);

  gemm_bt_f32<<<dim3(M_TOK / 128, D_ / 128), 256, 0, stream>>>(
      O, Wp_t, bproj, x, out, M_TOK, D_, D_);
}